// Round 1
// baseline (2694.038 us; speedup 1.0000x reference)
//
#include <hip/hip_runtime.h>

#define B_TOT   1024
#define TM1     127
#define NE      128
#define STRIDE  129          // +1 pad -> 2-way bank aliasing only (free)
#define NTHREADS 512
#define NBLOCKS  256
#define ROUNDS  (B_TOT / NBLOCKS)

__device__ __forceinline__ float fast_tanh(float x) {
    float e = __expf(2.0f * x);                       // overflow->inf -> tanh=1 (correct)
    return 1.0f - 2.0f * __builtin_amdgcn_rcpf(e + 1.0f);
}
__device__ __forceinline__ float fast_sig(float x) {
    return __builtin_amdgcn_rcpf(1.0f + __expf(-x));
}

__global__ __launch_bounds__(NTHREADS, 2)
void decoder_kernel(const float* __restrict__ Xg,     // (B,127,128)
                    const float* __restrict__ yprev,  // (B,127)
                    const float* __restrict__ W1,     // (384,128): rows [d(128); c(128); x(128)]
                    const float* __restrict__ b1,     // (128)
                    const float* __restrict__ W2,     // (128)
                    const float* __restrict__ b2v,    // (1)
                    const float* __restrict__ Wfc,    // (129)
                    const float* __restrict__ bfcv,   // (1)
                    const float* __restrict__ Wx,     // (512)
                    const float* __restrict__ Wh,     // (128,512)
                    const float* __restrict__ blv,    // (512)
                    const float* __restrict__ Wf,     // (256)
                    const float* __restrict__ bfv,    // (1)
                    float* __restrict__ out)          // (B)
{
    __shared__ float Xs  [128 * STRIDE];   // X slice, row 127 zeroed
    __shared__ float preX[128 * STRIDE];   // X@W1_x + b1
    __shared__ float sdc [256];            // d(0..127), c(128..255)
    __shared__ float2 u2 [128];            // (u[e], W2[e])
    __shared__ float betas[128];           // beta, [127] stays 0
    __shared__ float ctxs[128];
    __shared__ float scr [NTHREADS];
    __shared__ float ytl_s;

    const int tid = threadIdx.x;
    const int e   = tid & 127;
    const int h   = tid >> 7;              // 0..3, wave-uniform
    const int l6  = tid & 63;

    // ---- register-cached weights (loaded once, reused 4 batches x 127 steps) ----
    float w1r[64];                          // W1[64h+i][e], rows 0..255 = [W1_d; W1_c]
    #pragma unroll
    for (int i = 0; i < 64; ++i) w1r[i] = W1[(h * 64 + i) * NE + e];
    float whr[128];                         // Wh[k][tid] -> this thread owns z-column tid
    #pragma unroll
    for (int k = 0; k < 128; ++k) whr[k] = Wh[k * 512 + tid];

    const float bl_r  = blv[tid];
    const float wx_r  = Wx[tid];
    const float b1r   = b1[e];
    const float w2r   = W2[e];
    const float b2r   = b2v[0];
    const float bfc_r = bfcv[0];
    const float wfcy  = Wfc[128];
    const float wfc0  = Wfc[l6];
    const float wfc1  = Wfc[l6 + 64];
    const float wf0   = Wf[l6];
    const float wf1   = Wf[l6 + 64];
    const float wf2   = Wf[l6 + 128];
    const float wf3   = Wf[l6 + 192];
    const float bf_r  = bfv[0];

    for (int r = 0; r < ROUNDS; ++r) {
        const int b = (int)blockIdx.x + r * NBLOCKS;
        const float* Xb = Xg + (size_t)b * (TM1 * NE);

        if (tid < 128) {
            float x00 = Xb[0];              // d0 = c0 = broadcast X[b,0,0]
            sdc[tid]       = x00;
            sdc[128 + tid] = x00;
            betas[tid]     = 0.0f;
        }
        #pragma unroll
        for (int i = 0; i < 32; ++i) {      // stage X slice (coalesced), zero row 127
            int tp = h * 32 + i;
            Xs[tp * STRIDE + e] = (tp < TM1) ? Xb[tp * NE + e] : 0.0f;
        }
        __syncthreads();

        // ---- preX[t'][e] = b1[e] + sum_k X[t',k] * W1_x[k][e] ----
        #pragma unroll
        for (int gg = 0; gg < 2; ++gg) {
            float acc[16];
            #pragma unroll
            for (int j = 0; j < 16; ++j) acc[j] = b1r;
            for (int k = 0; k < 128; ++k) {
                float w = W1[(256 + k) * NE + e];              // coalesced, L2-hot
                #pragma unroll
                for (int j = 0; j < 16; ++j)                   // Xs reads are broadcasts
                    acc[j] = fmaf(w, Xs[(h * 32 + gg * 16 + j) * STRIDE + k], acc[j]);
            }
            #pragma unroll
            for (int j = 0; j < 16; ++j)
                preX[(h * 32 + gg * 16 + j) * STRIDE + e] = acc[j];
        }
        __syncthreads();

        for (int t = 0; t < TM1; ++t) {
            // A: u[e] = sum_k [d;c][k] * W1dc[k][e]   (4-way k-split over h)
            float pa = 0.0f;
            #pragma unroll
            for (int i = 0; i < 64; ++i) pa = fmaf(w1r[i], sdc[h * 64 + i], pa);
            scr[tid] = pa;
            __syncthreads();
            if (tid < 128) {
                float u = scr[tid] + scr[tid + 128] + scr[tid + 256] + scr[tid + 384];
                u2[tid] = make_float2(u, w2r);
            }
            __syncthreads();

            // B: beta[t'] = b2 + sum_e W2[e]*tanh(preX[t',e]+u[e])  (t'=tid&127, 4-way e-split)
            {
                float p = 0.0f;
                #pragma unroll
                for (int i = 0; i < 32; ++i) {
                    int ee = h * 32 + i;
                    float2 uw = u2[ee];                        // b64 broadcast
                    float hx = fast_tanh(preX[e * STRIDE + ee] + uw.x); // 2 lanes/bank: free
                    p = fmaf(hx, uw.y, p);
                }
                scr[tid] = p;
            }
            __syncthreads();
            if (tid < TM1)
                betas[tid] = b2r + scr[tid] + scr[tid + 128] + scr[tid + 256] + scr[tid + 384];
            __syncthreads();

            // C: ctx[e] = sum_t' beta[t'] * X[t',e]   (4-way t'-split over h)
            {
                float p = 0.0f;
                #pragma unroll
                for (int i = 0; i < 32; ++i) {
                    int tp = h * 32 + i;                       // beta[127]=0, Xs row127=0
                    p = fmaf(betas[tp], Xs[tp * STRIDE + e], p);
                }
                scr[tid] = p;
            }
            __syncthreads();
            if (tid < 128)
                ctxs[tid] = scr[tid] + scr[tid + 128] + scr[tid + 256] + scr[tid + 384];
            __syncthreads();

            // D: y_tilde = ctx.Wfc[:128] + y_t*Wfc[128] + bfc   (wave 0 shuffle-reduce)
            if (tid < 64) {
                float p = fmaf(ctxs[tid], wfc0, ctxs[tid + 64] * wfc1);
                #pragma unroll
                for (int off = 32; off > 0; off >>= 1) p += __shfl_down(p, off);
                if (tid == 0)
                    ytl_s = p + bfc_r + yprev[(size_t)b * TM1 + t] * wfcy;
            }
            __syncthreads();

            // E: z[j=tid] = bl + y_tilde*Wx + sum_k d[k]*Wh[k][j]; then LSTM gates
            {
                float p = fmaf(ytl_s, wx_r, bl_r);
                #pragma unroll
                for (int k = 0; k < 128; ++k) p = fmaf(whr[k], sdc[k], p);  // sdc broadcast
                scr[tid] = p;
            }
            __syncthreads();
            if (tid < 128) {
                float zi = scr[tid];
                float zf = scr[tid + 128];
                float zg = scr[tid + 256];
                float zo = scr[tid + 384];
                float cn = fast_sig(zf) * sdc[128 + tid] + fast_sig(zi) * fast_tanh(zg);
                float dn = fast_sig(zo) * fast_tanh(cn);
                sdc[tid]       = dn;
                sdc[128 + tid] = cn;
            }
            __syncthreads();
        }

        // out[b] = [d; ctx] . Wf + bf
        if (tid < 64) {
            float p = sdc[tid] * wf0 + sdc[tid + 64] * wf1
                    + ctxs[tid] * wf2 + ctxs[tid + 64] * wf3;
            #pragma unroll
            for (int off = 32; off > 0; off >>= 1) p += __shfl_down(p, off);
            if (tid == 0) out[b] = p + bf_r;
        }
        __syncthreads();
    }
}

extern "C" void kernel_launch(void* const* d_in, const int* in_sizes, int n_in,
                              void* d_out, int out_size, void* d_ws, size_t ws_size,
                              hipStream_t stream) {
    (void)in_sizes; (void)n_in; (void)d_ws; (void)ws_size; (void)out_size;
    const float* Xg    = (const float*)d_in[0];
    const float* yprev = (const float*)d_in[1];
    const float* W1    = (const float*)d_in[2];
    const float* b1    = (const float*)d_in[3];
    const float* W2    = (const float*)d_in[4];
    const float* b2    = (const float*)d_in[5];
    const float* Wfc   = (const float*)d_in[6];
    const float* bfc   = (const float*)d_in[7];
    const float* Wx    = (const float*)d_in[8];
    const float* Wh    = (const float*)d_in[9];
    const float* bl    = (const float*)d_in[10];
    const float* Wf    = (const float*)d_in[11];
    const float* bf    = (const float*)d_in[12];
    decoder_kernel<<<NBLOCKS, NTHREADS, 0, stream>>>(
        Xg, yprev, W1, b1, W2, b2, Wfc, bfc, Wx, Wh, bl, Wf, bf, (float*)d_out);
}